// Round 1
// baseline (545.888 us; speedup 1.0000x reference)
//
#include <hip/hip_runtime.h>

// Problem constants (from reference): inputs (16, 512, 64, 192) fp32
constexpr int Bq = 16;
constexpr int Cc = 256;          // channels per half (x1 / x2)
constexpr int Hh = 64;
constexpr int Ww = 192;
constexpr int Dd = 25;           // MAX_DISP + 1
constexpr int HW = Hh * Ww;      // 12288 (channel stride)
constexpr int BSTRIDE = 2 * Cc * HW;  // batch stride in floats
constexpr int CPR = 4;           // channels staged per round
constexpr int NR = Cc / CPR;     // 64 rounds
constexpr int ROWP = 24 + Ww;    // LDS row: 24-zero left pad + 192 data

// Kernel 1: corr[b,d,h,w] = sum_c x1[b,c,h,w] * x2[b,c,h,w-d]  (0 if w-d<0)
// Block = 192 threads = 2 h-rows x 96 lanes; each lane owns w0=2u, w0+1.
__global__ __launch_bounds__(192) void corr_kernel(const float* __restrict__ in,
                                                   float* __restrict__ corr) {
  const int t   = threadIdx.x;
  const int hg  = blockIdx.x;    // 0..31 (h pair)
  const int b   = blockIdx.y;    // 0..15
  const int row = t / 96;        // which of the 2 h-rows
  const int u   = t % 96;
  const int w0  = 2 * u;
  const int h   = hg * 2 + row;

  __shared__ float x2s[2][CPR][ROWP];

  // Zero the 24-float left pads once: 2*4*24 = 192 writes = blockDim exactly.
  {
    const int r2  = t / (CPR * 24);
    const int rem = t % (CPR * 24);
    x2s[r2][rem / 24][rem % 24] = 0.0f;
  }

  const float* x1p = in + (size_t)b * BSTRIDE + (size_t)h * Ww + w0;
  const float* x2p = x1p + (size_t)Cc * HW;

  float2 acc[Dd];
#pragma unroll
  for (int d = 0; d < Dd; ++d) acc[d] = make_float2(0.0f, 0.0f);

  // Prefetch round 0 (4 channels of x1 to regs, x2 to regs for LDS staging)
  float2 px1[CPR], px2[CPR];
#pragma unroll
  for (int c = 0; c < CPR; ++c) {
    px1[c] = *(const float2*)(x1p + c * HW);
    px2[c] = *(const float2*)(x2p + c * HW);
  }

  for (int rnd = 0; rnd < NR; ++rnd) {
    __syncthreads();  // previous round finished reading LDS
    float2 cx1[CPR];
#pragma unroll
    for (int c = 0; c < CPR; ++c) {
      cx1[c] = px1[c];
      *(float2*)&x2s[row][c][24 + w0] = px2[c];
    }
    __syncthreads();  // staging visible

    // Issue next round's global loads AFTER the barrier so the barrier's
    // vmcnt(0) drain doesn't serialize them; compute below hides latency.
    if (rnd + 1 < NR) {
      const float* p1 = x1p + (size_t)(rnd + 1) * CPR * HW;
      const float* p2 = p1 + (size_t)Cc * HW;
#pragma unroll
      for (int c = 0; c < CPR; ++c) {
        px1[c] = *(const float2*)(p1 + c * HW);
        px2[c] = *(const float2*)(p2 + c * HW);
      }
    }

#pragma unroll
    for (int c = 0; c < CPR; ++c) {
      // Sliding window x2[w0-24 .. w0+1] via 13 aligned ds_read_b64
      float win[26];
#pragma unroll
      for (int k = 0; k < 13; ++k) {
        const float2 v = *(const float2*)&x2s[row][c][w0 + 2 * k];
        win[2 * k]     = v.x;
        win[2 * k + 1] = v.y;
      }
      const float a0 = cx1[c].x, a1 = cx1[c].y;
#pragma unroll
      for (int d = 0; d < Dd; ++d) {
        acc[d].x = fmaf(a0, win[24 - d], acc[d].x);
        acc[d].y = fmaf(a1, win[25 - d], acc[d].y);
      }
    }
  }

  // corr layout (b, d, h, w); stride per d is Hh*Ww == HW
  float* cp = corr + ((size_t)b * Dd * Hh + h) * Ww + w0;
#pragma unroll
  for (int d = 0; d < Dd; ++d)
    *(float2*)(cp + (size_t)d * HW) = acc[d];
}

// Kernel 2: depthwise 3x3 box filter with zero padding (all-ones weights)
__global__ __launch_bounds__(192) void box_kernel(const float* __restrict__ corr,
                                                  float* __restrict__ out) {
  const int w  = threadIdx.x;   // 0..191
  const int h  = blockIdx.x;    // 0..63
  const int bd = blockIdx.y;    // 0..399 (b*25 + d)
  const float* base = corr + ((size_t)bd * Hh + h) * Ww;

  float s = 0.0f;
#pragma unroll
  for (int dh = -1; dh <= 1; ++dh) {
    const int hh = h + dh;
    if (hh < 0 || hh >= Hh) continue;
    const float* r = base + dh * Ww;
    s += r[w];
    if (w > 0)      s += r[w - 1];
    if (w < Ww - 1) s += r[w + 1];
  }
  out[((size_t)bd * Hh + h) * Ww + w] = s;
}

extern "C" void kernel_launch(void* const* d_in, const int* in_sizes, int n_in,
                              void* d_out, int out_size, void* d_ws, size_t ws_size,
                              hipStream_t stream) {
  const float* in = (const float*)d_in[0];
  float* out  = (float*)d_out;
  float* corr = (float*)d_ws;   // 16*25*64*192*4 = 19.66 MB scratch, fully overwritten

  dim3 g1(Hh / 2, Bq);          // (32, 16) = 512 blocks
  corr_kernel<<<g1, 192, 0, stream>>>(in, corr);

  dim3 g2(Hh, Bq * Dd);         // (64, 400)
  box_kernel<<<g2, Ww, 0, stream>>>(corr, out);
}